// Round 7
// baseline (681.634 us; speedup 1.0000x reference)
//
#include <hip/hip_runtime.h>

// Langevin dynamics, bit-matched to JAX Threefry-2x32 *partitionable* RNG:
//   split(key, n):  keys[t] = threefry2x32(key=(0,1), counter=(0, t))
//   random_bits32:  bits[i] = o0 ^ o1 of threefry2x32(key_t, counter=(0, i))
// R7: occupancy attack. 128-thread blocks x 4096 (16 blocks/CU candidate),
// LDS cut to 4 KB (2 raw key words/step, schedule expanded in-loop, both
// steps' keys in ONE ds_read_b128/iter). Normal-generation math on float2
// ext-vectors to bait v_pk_fma_f32/v_pk_mul_f32 (CDNA4 full-rate packed).

typedef float v2f __attribute__((ext_vector_type(2)));

__device__ __forceinline__ void tf2x32(unsigned k0, unsigned k1,
                                       unsigned c0, unsigned c1,
                                       unsigned& o0, unsigned& o1) {
  const unsigned k2 = k0 ^ k1 ^ 0x1BD11BDAu;
  unsigned x0 = c0 + k0, x1 = c1 + k1;
#define TF1(R) x0 += x1; x1 = ((x1 << (R)) | (x1 >> (32 - (R)))); x1 ^= x0;
  TF1(13) TF1(15) TF1(26) TF1(6)  x0 += k1; x1 += k2 + 1u;
  TF1(17) TF1(29) TF1(16) TF1(24) x0 += k2; x1 += k0 + 2u;
  TF1(13) TF1(15) TF1(26) TF1(6)  x0 += k0; x1 += k1 + 3u;
  TF1(17) TF1(29) TF1(16) TF1(24) x0 += k1; x1 += k2 + 4u;
  TF1(13) TF1(15) TF1(26) TF1(6)  x0 += k2; x1 += k0 + 5u;
#undef TF1
  o0 = x0; o1 = x1;
}

// Two interleaved threefry chains for steps t (keys ka0,ka1) and t+1
// (kb0,kb1), same counter (0, cj). k2/injection constants built inline.
__device__ __forceinline__ void tf_fold2k(unsigned ka0, unsigned ka1,
                                          unsigned kb0, unsigned kb1,
                                          unsigned cj,
                                          unsigned& ra, unsigned& rb) {
  const unsigned ka2 = ka0 ^ ka1 ^ 0x1BD11BDAu;
  const unsigned kb2 = kb0 ^ kb1 ^ 0x1BD11BDAu;
  unsigned a0 = ka0, a1 = cj + ka1;
  unsigned b0 = kb0, b1 = cj + kb1;
#define TFR2(R)                                   \
  a0 += a1; b0 += b1;                             \
  a1 = ((a1 << (R)) | (a1 >> (32 - (R)))) ^ a0;   \
  b1 = ((b1 << (R)) | (b1 >> (32 - (R)))) ^ b0;
  TFR2(13) TFR2(15) TFR2(26) TFR2(6)
  a0 += ka1; b0 += kb1; a1 += ka2 + 1u; b1 += kb2 + 1u;
  TFR2(17) TFR2(29) TFR2(16) TFR2(24)
  a0 += ka2; b0 += kb2; a1 += ka0 + 2u; b1 += kb0 + 2u;
  TFR2(13) TFR2(15) TFR2(26) TFR2(6)
  a0 += ka0; b0 += kb0; a1 += ka1 + 3u; b1 += kb1 + 3u;
  TFR2(17) TFR2(29) TFR2(16) TFR2(24)
  a0 += ka1; b0 += kb1; a1 += ka2 + 4u; b1 += kb2 + 4u;
  TFR2(13) TFR2(15) TFR2(26) TFR2(6)
  a0 += ka2; b0 += kb2; a1 += ka0 + 5u; b1 += kb0 + 5u;
#undef TFR2
  ra = a0 ^ a1;
  rb = b0 ^ b1;
}

// uniform(-0.99999994, 1) -> sqrt(2)*erfinv(u): XLA ErfInv32 (Giles) poly,
// two normals as float2 so poly/muls lower to v_pk_fma_f32/v_pk_mul_f32.
// Identical IEEE f32 per half. log1p(-m) via hw log2 * ln2 (~2-ulp vs XLA).
__device__ __forceinline__ void b2n2(unsigned bba, unsigned bbb,
                                     float& na, float& nb) {
  v2f f;
  f.x = __uint_as_float((bba >> 9) | 0x3F800000u) - 1.0f;
  f.y = __uint_as_float((bbb >> 9) | 0x3F800000u) - 1.0f;
  const v2f u = __builtin_elementwise_fma(f, (v2f)2.0f, (v2f)(-0.99999994f));
  const v2f m = u * u;
  const v2f tt = (v2f)1.0f - m;
  v2f l;
  l.x = __log2f(tt.x);
  l.y = __log2f(tt.y);
  const v2f w = l * (v2f)(-0.693147180559945f);
  const bool sa = w.x < 5.0f, sb = w.y < 5.0f;
  const v2f zc = w - (v2f)2.5f;  // central-branch z, packed
  v2f z;
  z.x = sa ? zc.x : (__builtin_amdgcn_sqrtf(w.x) - 3.0f);
  z.y = sb ? zc.y : (__builtin_amdgcn_sqrtf(w.y) - 3.0f);
#define SEL2(A, B) (v2f){sa ? (A) : (B), sb ? (A) : (B)}
  v2f p = SEL2(2.81022636e-08f, -0.000200214257f);
  p = __builtin_elementwise_fma(p, z, SEL2(3.43273939e-07f, 0.000100950558f));
  p = __builtin_elementwise_fma(p, z, SEL2(-3.5233877e-06f, 0.00134934322f));
  p = __builtin_elementwise_fma(p, z, SEL2(-4.39150654e-06f, -0.00367342844f));
  p = __builtin_elementwise_fma(p, z, SEL2(0.00021858087f, 0.00573950773f));
  p = __builtin_elementwise_fma(p, z, SEL2(-0.00125372503f, -0.0076224613f));
  p = __builtin_elementwise_fma(p, z, SEL2(-0.00417768164f, 0.00943887047f));
  p = __builtin_elementwise_fma(p, z, SEL2(0.246640727f, 1.00167406f));
  p = __builtin_elementwise_fma(p, z, SEL2(1.50140941f, 2.83297682f));
#undef SEL2
  const v2f n = (p * u) * (v2f)__uint_as_float(0x3FB504F3u);  // * sqrt(2)
  na = n.x;
  nb = n.y;
}

__global__ __launch_bounds__(128, 8) void langevin_tf(
    const float* __restrict__ x0p, const float* __restrict__ bias,
    const int* __restrict__ nsteps_p, float* __restrict__ out,
    int N, int ndim) {
  // Raw step keys only: 2 words/step -> 4 KB for 512 steps.
  __shared__ __align__(16) unsigned skeys[512 * 2];
  const int n_steps = __builtin_amdgcn_readfirstlane(nsteps_p[0]);
  const int nfill = n_steps < 512 ? n_steps : 512;
  for (int l = (int)threadIdx.x; l < nfill; l += (int)blockDim.x) {
    unsigned o0, o1;
    tf2x32(0u, 1u, 0u, (unsigned)l, o0, o1);
    skeys[2 * l] = o0;
    skeys[2 * l + 1] = o1;
  }
  __syncthreads();

  const int j = (int)(blockIdx.x * blockDim.x + threadIdx.x);
  if (j >= N) return;
  const unsigned cj = (unsigned)j;
  float x = x0p[j];
  const float b = bias[j % ndim];

  if (n_steps <= 512) {
    const uint4* sk4 = (const uint4*)skeys;  // steps (2i, 2i+1) per uint4
    int t = 0;
#pragma unroll 1
    for (; t + 1 < n_steps; t += 2) {
      const uint4 kk = sk4[t >> 1];  // ONE ds_read_b128: keys for t and t+1
      unsigned ra, rb;
      tf_fold2k(kk.x, kk.y, kk.z, kk.w, cj, ra, rb);
      float na, nb;
      b2n2(ra, rb, na, nb);
      // grad = 2*J2*x + 4*J4*x^3 + b = -2x + ((2x)*x)*x + b (ref assoc order)
      float g = -2.0f * x + ((2.0f * x) * x) * x + b;
      x = (x - g * 0.01f) + na * 0.1f;
      g = -2.0f * x + ((2.0f * x) * x) * x + b;
      x = (x - g * 0.01f) + nb * 0.1f;
    }
    if (t < n_steps) {  // odd-step tail
      const unsigned o0 = skeys[2 * t], o1 = skeys[2 * t + 1];
      unsigned ra, rb;
      tf_fold2k(o0, o1, o0, o1, cj, ra, rb);  // rb unused
      float na, nb;
      b2n2(ra, ra, na, nb);
      const float g = -2.0f * x + ((2.0f * x) * x) * x + b;
      x = (x - g * 0.01f) + na * 0.1f;
    }
  } else {
    // Fallback for n_steps > 512: recompute step keys inline, 2 steps/iter.
    for (int t = 0; t < n_steps; t += 2) {
      unsigned oa0, oa1, ob0, ob1;
      tf2x32(0u, 1u, 0u, (unsigned)t, oa0, oa1);
      tf2x32(0u, 1u, 0u, (unsigned)(t + 1), ob0, ob1);
      unsigned ra, rb;
      tf_fold2k(oa0, oa1, ob0, ob1, cj, ra, rb);
      float na, nb;
      b2n2(ra, rb, na, nb);
      float g = -2.0f * x + ((2.0f * x) * x) * x + b;
      x = (x - g * 0.01f) + na * 0.1f;
      if (t + 1 < n_steps) {
        g = -2.0f * x + ((2.0f * x) * x) * x + b;
        x = (x - g * 0.01f) + nb * 0.1f;
      }
    }
  }
  out[j] = x;
}

extern "C" void kernel_launch(void* const* d_in, const int* in_sizes, int n_in,
                              void* d_out, int out_size, void* d_ws, size_t ws_size,
                              hipStream_t stream) {
  (void)n_in; (void)d_ws; (void)ws_size; (void)out_size;
  const float* x0 = (const float*)d_in[0];
  const float* b = (const float*)d_in[1];
  const int* ns = (const int*)d_in[2];
  float* out = (float*)d_out;

  const int n = in_sizes[0];     // 2048*256 = 524288
  const int ndim = in_sizes[1];  // 256
  const int block = 128;
  const int grid = (n + block - 1) / block;  // 4096 blocks -> 16/CU candidate
  hipLaunchKernelGGL(langevin_tf, dim3(grid), dim3(block), 0, stream,
                     x0, b, ns, out, n, ndim);
}

// Round 8
// 573.541 us; speedup vs baseline: 1.1885x; 1.1885x over previous
//
#include <hip/hip_runtime.h>

// Langevin dynamics, bit-matched to JAX Threefry-2x32 *partitionable* RNG:
//   split(key, n):  keys[t] = threefry2x32(key=(0,1), counter=(0, t))
//   random_bits32:  bits[i] = o0 ^ o1 of threefry2x32(key_t, counter=(0, i))
// R8: instruction-count surgery. ~100 VALU instr/step (was ~120):
//  - erfinv tail (w>=5, 0.34%/lane) moved to __any-guarded rare block
//  - update folded: x' = fma(x,1.02, fma(x^3,-0.02, fma(p*u, 0.1*sqrt2, -0.01b)))
//  - k2 precomputed in LDS (uint4/step), +c injections as v_add3
//  - poly coefficients pinned to SGPRs via readfirstlane (VOP3 can't take
//    literals; prevents in-loop v_mov rematerialization)

__device__ __forceinline__ float sconst(float v) {
  return __uint_as_float(__builtin_amdgcn_readfirstlane(__float_as_uint(v)));
}

__device__ __forceinline__ void tf2x32(unsigned k0, unsigned k1,
                                       unsigned c0, unsigned c1,
                                       unsigned& o0, unsigned& o1) {
  const unsigned k2 = k0 ^ k1 ^ 0x1BD11BDAu;
  unsigned x0 = c0 + k0, x1 = c1 + k1;
#define TF1(R) x0 += x1; x1 = ((x1 << (R)) | (x1 >> (32 - (R)))); x1 ^= x0;
  TF1(13) TF1(15) TF1(26) TF1(6)  x0 += k1; x1 += k2 + 1u;
  TF1(17) TF1(29) TF1(16) TF1(24) x0 += k2; x1 += k0 + 2u;
  TF1(13) TF1(15) TF1(26) TF1(6)  x0 += k0; x1 += k1 + 3u;
  TF1(17) TF1(29) TF1(16) TF1(24) x0 += k1; x1 += k2 + 4u;
  TF1(13) TF1(15) TF1(26) TF1(6)  x0 += k2; x1 += k0 + 5u;
#undef TF1
  o0 = x0; o1 = x1;
}

// Two statement-interleaved threefry chains, keys {ka.x,ka.y,ka.z=k2} and
// {kb.x,kb.y,kb.z}, counter (0, cj). "+ const" injections shaped for v_add3.
__device__ __forceinline__ void tf_fold2k(uint4 ka, uint4 kb, unsigned cj,
                                          unsigned& ra, unsigned& rb) {
  unsigned a0 = ka.x, a1 = cj + ka.y;
  unsigned b0 = kb.x, b1 = cj + kb.y;
#define TFR2(R)                                   \
  a0 += a1; b0 += b1;                             \
  a1 = ((a1 << (R)) | (a1 >> (32 - (R)))) ^ a0;   \
  b1 = ((b1 << (R)) | (b1 >> (32 - (R)))) ^ b0;
  TFR2(13) TFR2(15) TFR2(26) TFR2(6)
  a0 += ka.y; b0 += kb.y; a1 = a1 + ka.z + 1u; b1 = b1 + kb.z + 1u;
  TFR2(17) TFR2(29) TFR2(16) TFR2(24)
  a0 += ka.z; b0 += kb.z; a1 = a1 + ka.x + 2u; b1 = b1 + kb.x + 2u;
  TFR2(13) TFR2(15) TFR2(26) TFR2(6)
  a0 += ka.x; b0 += kb.x; a1 = a1 + ka.y + 3u; b1 = b1 + kb.y + 3u;
  TFR2(17) TFR2(29) TFR2(16) TFR2(24)
  a0 += ka.y; b0 += kb.y; a1 = a1 + ka.z + 4u; b1 = b1 + kb.z + 4u;
  TFR2(13) TFR2(15) TFR2(26) TFR2(6)
  a0 += ka.z; b0 += kb.z; a1 = a1 + ka.x + 5u; b1 = b1 + kb.x + 5u;
#undef TFR2
  ra = a0 ^ a1;
  rb = b0 ^ b1;
}

__global__ __launch_bounds__(256, 8) void langevin_tf(
    const float* __restrict__ x0p, const float* __restrict__ bias,
    const int* __restrict__ nsteps_p, float* __restrict__ out,
    int N, int ndim) {
  // Key table: {k0, k1, k2, pad} per step -> one ds_read_b128 per step.
  __shared__ __align__(16) uint4 skeys[512];
  const int n_steps = __builtin_amdgcn_readfirstlane(nsteps_p[0]);
  const int nfill = n_steps < 512 ? n_steps : 512;
  for (int l = (int)threadIdx.x; l < nfill; l += (int)blockDim.x) {
    unsigned o0, o1;
    tf2x32(0u, 1u, 0u, (unsigned)l, o0, o1);
    skeys[l] = make_uint4(o0, o1, o0 ^ o1 ^ 0x1BD11BDAu, 0u);
  }
  __syncthreads();

  const int j = (int)(blockIdx.x * blockDim.x + threadIdx.x);
  if (j >= N) return;
  const unsigned cj = (unsigned)j;
  float x = x0p[j];
  const float b = bias[j % ndim];

  // SGPR-pinned constants (loop-invariant; VOP3 fma reads 1 SGPR legally).
  const float LO = sconst(-0.99999994f);      // nextafter(-1, 0)
  const float NLN2 = sconst(-0.693147180559945f);
  const float C8 = sconst(2.81022636e-08f), C7 = sconst(3.43273939e-07f);
  const float C6 = sconst(-3.5233877e-06f), C5 = sconst(-4.39150654e-06f);
  const float C4 = sconst(0.00021858087f),  C3 = sconst(-0.00125372503f);
  const float C2 = sconst(-0.00417768164f), C1 = sconst(0.246640727f);
  const float C0 = sconst(1.50140941f);
  const float T8 = sconst(-0.000200214257f), T7 = sconst(0.000100950558f);
  const float T6 = sconst(0.00134934322f),   T5 = sconst(-0.00367342844f);
  const float T4 = sconst(0.00573950773f),   T3 = sconst(-0.0076224613f);
  const float T2 = sconst(0.00943887047f),   T1 = sconst(1.00167406f);
  const float T0 = sconst(2.83297682f);
  const float CS = sconst(0.1f * __uint_as_float(0x3FB504F3u));  // 0.1*sqrt2
  const float A1 = sconst(1.02f);   // 1 - 2*J2*DT
  const float A3 = sconst(-0.02f);  // -4*J4*DT
  const float bp = b * -0.01f;      // -DT*b (per-lane)

  if (n_steps <= 512) {
    int t = 0;
#pragma unroll 1
    for (; t + 1 < n_steps; t += 2) {
      const uint4 ka = skeys[t];
      const uint4 kb = skeys[t + 1];
      unsigned ra, rb;
      tf_fold2k(ka, kb, cj, ra, rb);  // steps t, t+1: independent chains
      // bits -> uniform(-0.99999994, 1)
      const float fa = __uint_as_float((ra >> 9) | 0x3F800000u) - 1.0f;
      const float fb = __uint_as_float((rb >> 9) | 0x3F800000u) - 1.0f;
      const float ua = fmaf(fa, 2.0f, LO);
      const float ub = fmaf(fb, 2.0f, LO);
      // w = -log1p(-u*u) via hw log2 (~2 ulp vs XLA)
      const float wa = __log2f(1.0f - ua * ua) * NLN2;
      const float wb = __log2f(1.0f - ub * ub) * NLN2;
      // central branch (w<5): covers 99.66% of lanes
      const float za = wa - 2.5f;
      const float zb = wb - 2.5f;
      float pa = C8, pb = C8;
      pa = fmaf(pa, za, C7); pb = fmaf(pb, zb, C7);
      pa = fmaf(pa, za, C6); pb = fmaf(pb, zb, C6);
      pa = fmaf(pa, za, C5); pb = fmaf(pb, zb, C5);
      pa = fmaf(pa, za, C4); pb = fmaf(pb, zb, C4);
      pa = fmaf(pa, za, C3); pb = fmaf(pb, zb, C3);
      pa = fmaf(pa, za, C2); pb = fmaf(pb, zb, C2);
      pa = fmaf(pa, za, C1); pb = fmaf(pb, zb, C1);
      pa = fmaf(pa, za, C0); pb = fmaf(pb, zb, C0);
      float ea = pa * ua;   // erfinv(ua)
      float eb = pb * ub;
      if (__any((wa >= 5.0f) | (wb >= 5.0f))) {  // rare tail, ~35% of waves
        const float qza = __builtin_amdgcn_sqrtf(wa) - 3.0f;
        const float qzb = __builtin_amdgcn_sqrtf(wb) - 3.0f;
        float qa = T8, qb = T8;
        qa = fmaf(qa, qza, T7); qb = fmaf(qb, qzb, T7);
        qa = fmaf(qa, qza, T6); qb = fmaf(qb, qzb, T6);
        qa = fmaf(qa, qza, T5); qb = fmaf(qb, qzb, T5);
        qa = fmaf(qa, qza, T4); qb = fmaf(qb, qzb, T4);
        qa = fmaf(qa, qza, T3); qb = fmaf(qb, qzb, T3);
        qa = fmaf(qa, qza, T2); qb = fmaf(qb, qzb, T2);
        qa = fmaf(qa, qza, T1); qb = fmaf(qb, qzb, T1);
        qa = fmaf(qa, qza, T0); qb = fmaf(qb, qzb, T0);
        ea = (wa >= 5.0f) ? qa * ua : ea;
        eb = (wb >= 5.0f) ? qb * ub : eb;
      }
      // x' = A1*x + A3*x^3 + (CS*erfinv + bp)
      float x3 = (x * x) * x;
      x = fmaf(x, A1, fmaf(x3, A3, fmaf(ea, CS, bp)));
      x3 = (x * x) * x;
      x = fmaf(x, A1, fmaf(x3, A3, fmaf(eb, CS, bp)));
    }
    if (t < n_steps) {  // odd-step tail
      const uint4 ka = skeys[t];
      unsigned ra, rb;
      tf_fold2k(ka, ka, cj, ra, rb);
      const float fa = __uint_as_float((ra >> 9) | 0x3F800000u) - 1.0f;
      const float ua = fmaf(fa, 2.0f, LO);
      const float wa = __log2f(1.0f - ua * ua) * NLN2;
      float pa, za;
      if (wa < 5.0f) { za = wa - 2.5f;
        pa = C8; pa = fmaf(pa, za, C7); pa = fmaf(pa, za, C6);
        pa = fmaf(pa, za, C5); pa = fmaf(pa, za, C4); pa = fmaf(pa, za, C3);
        pa = fmaf(pa, za, C2); pa = fmaf(pa, za, C1); pa = fmaf(pa, za, C0);
      } else { za = __builtin_amdgcn_sqrtf(wa) - 3.0f;
        pa = T8; pa = fmaf(pa, za, T7); pa = fmaf(pa, za, T6);
        pa = fmaf(pa, za, T5); pa = fmaf(pa, za, T4); pa = fmaf(pa, za, T3);
        pa = fmaf(pa, za, T2); pa = fmaf(pa, za, T1); pa = fmaf(pa, za, T0);
      }
      const float ea = pa * ua;
      const float x3 = (x * x) * x;
      x = fmaf(x, A1, fmaf(x3, A3, fmaf(ea, CS, bp)));
    }
  } else {
    // Fallback for n_steps > 512: recompute step keys inline, 1 step/iter.
    for (int t = 0; t < n_steps; ++t) {
      unsigned o0, o1;
      tf2x32(0u, 1u, 0u, (unsigned)t, o0, o1);
      const uint4 ka = make_uint4(o0, o1, o0 ^ o1 ^ 0x1BD11BDAu, 0u);
      unsigned ra, rb;
      tf_fold2k(ka, ka, cj, ra, rb);
      const float fa = __uint_as_float((ra >> 9) | 0x3F800000u) - 1.0f;
      const float ua = fmaf(fa, 2.0f, LO);
      const float wa = __log2f(1.0f - ua * ua) * NLN2;
      float pa, za;
      if (wa < 5.0f) { za = wa - 2.5f;
        pa = C8; pa = fmaf(pa, za, C7); pa = fmaf(pa, za, C6);
        pa = fmaf(pa, za, C5); pa = fmaf(pa, za, C4); pa = fmaf(pa, za, C3);
        pa = fmaf(pa, za, C2); pa = fmaf(pa, za, C1); pa = fmaf(pa, za, C0);
      } else { za = __builtin_amdgcn_sqrtf(wa) - 3.0f;
        pa = T8; pa = fmaf(pa, za, T7); pa = fmaf(pa, za, T6);
        pa = fmaf(pa, za, T5); pa = fmaf(pa, za, T4); pa = fmaf(pa, za, T3);
        pa = fmaf(pa, za, T2); pa = fmaf(pa, za, T1); pa = fmaf(pa, za, T0);
      }
      const float ea = pa * ua;
      const float x3 = (x * x) * x;
      x = fmaf(x, A1, fmaf(x3, A3, fmaf(ea, CS, bp)));
    }
  }
  out[j] = x;
}

extern "C" void kernel_launch(void* const* d_in, const int* in_sizes, int n_in,
                              void* d_out, int out_size, void* d_ws, size_t ws_size,
                              hipStream_t stream) {
  (void)n_in; (void)d_ws; (void)ws_size; (void)out_size;
  const float* x0 = (const float*)d_in[0];
  const float* b = (const float*)d_in[1];
  const int* ns = (const int*)d_in[2];
  float* out = (float*)d_out;

  const int n = in_sizes[0];     // 2048*256 = 524288
  const int ndim = in_sizes[1];  // 256
  const int block = 256;
  const int grid = (n + block - 1) / block;  // 2048 blocks -> 8/CU
  hipLaunchKernelGGL(langevin_tf, dim3(grid), dim3(block), 0, stream,
                     x0, b, ns, out, n, ndim);
}